// Round 3
// baseline (285.320 us; speedup 1.0000x reference)
//
#include <hip/hip_runtime.h>

#define BLOCK 256
#define GRID 2048   // GRID*BLOCK float4-groups == NPIX/4 exactly

namespace {
constexpr int C = 21;
constexpr int HW = 512 * 512;          // 262144 = 2^18
constexpr int NPIX = 8 * HW;           // 2097152
constexpr int NGRP = NPIX / 4;         // 524288 = GRID*BLOCK
constexpr int CH4 = HW / 4;            // channel stride in float4 units
constexpr float EPS = 1e-8f;
constexpr int WS_CNT = C * C;
constexpr int WS_LOGP = C * C + C;
constexpr int ACC_USED = C * C + C + 1;   // 463
constexpr int ACC_STRIDE = 464;
constexpr int MAX_COPIES = 64;
}

__global__ __launch_bounds__(BLOCK, 4) void wce_main(const float* __restrict__ inp,
                                                     const float* __restrict__ tgt,
                                                     float* __restrict__ acc,
                                                     int copy_mask) {
    __shared__ float sS[C * C];
    __shared__ float sCnt[C];
    __shared__ float sRed[BLOCK / 64];

    const int tid = threadIdx.x;
    for (int i = tid; i < C * C; i += BLOCK) sS[i] = 0.f;
    if (tid < C) sCnt[tid] = 0.f;
    __syncthreads();

    const int g = blockIdx.x * BLOCK + tid;      // one float4 group per thread
    const int pix0 = g << 2;
    const int n = pix0 >> 18;                    // / HW
    const int hw = pix0 & (HW - 1);
    const size_t base = (size_t)n * (size_t)(C * HW) + (size_t)hw;

    // ---- phase 1: 21 independent target loads -> argmax ----
    const float4* __restrict__ tp = reinterpret_cast<const float4*>(tgt + base);
    float4 t[C];
#pragma unroll
    for (int c = 0; c < C; ++c) t[c] = tp[c * CH4];

    float4 bv = t[0];
    int bx = 0, by = 0, bz = 0, bw = 0;
#pragma unroll
    for (int c = 1; c < C; ++c) {
        if (t[c].x > bv.x) { bv.x = t[c].x; bx = c; }
        if (t[c].y > bv.y) { bv.y = t[c].y; by = c; }
        if (t[c].z > bv.z) { bv.z = t[c].z; bz = c; }
        if (t[c].w > bv.w) { bv.w = t[c].w; bw = c; }
    }

    // ---- phase 2: 21 independent input loads -> softmax ----
    const float4* __restrict__ ip = reinterpret_cast<const float4*>(inp + base);
    float4 x[C];
#pragma unroll
    for (int c = 0; c < C; ++c) x[c] = ip[c * CH4];

    float4 m = x[0];
#pragma unroll
    for (int c = 1; c < C; ++c) {
        m.x = fmaxf(m.x, x[c].x);
        m.y = fmaxf(m.y, x[c].y);
        m.z = fmaxf(m.z, x[c].z);
        m.w = fmaxf(m.w, x[c].w);
    }

    float4 xlab = x[0];
#pragma unroll
    for (int c = 1; c < C; ++c) {
        if (bx == c) xlab.x = x[c].x;
        if (by == c) xlab.y = x[c].y;
        if (bz == c) xlab.z = x[c].z;
        if (bw == c) xlab.w = x[c].w;
    }

    float4 s = make_float4(0.f, 0.f, 0.f, 0.f);
#pragma unroll
    for (int c = 0; c < C; ++c) {
        x[c].x = __expf(x[c].x - m.x); s.x += x[c].x;
        x[c].y = __expf(x[c].y - m.y); s.y += x[c].y;
        x[c].z = __expf(x[c].z - m.z); s.z += x[c].z;
        x[c].w = __expf(x[c].w - m.w); s.w += x[c].w;
    }

    float lp = (xlab.x - m.x - __logf(s.x))
             + (xlab.y - m.y - __logf(s.y))
             + (xlab.z - m.z - __logf(s.z))
             + (xlab.w - m.w - __logf(s.w));

    // ---- scatter p into S columns + counts ----
    const float ix = 1.f / s.x, iy = 1.f / s.y, iz = 1.f / s.z, iw = 1.f / s.w;
#pragma unroll
    for (int c = 0; c < C; ++c) {
        unsafeAtomicAdd(&sS[c * C + bx], x[c].x * ix);
        unsafeAtomicAdd(&sS[c * C + by], x[c].y * iy);
        unsafeAtomicAdd(&sS[c * C + bz], x[c].z * iz);
        unsafeAtomicAdd(&sS[c * C + bw], x[c].w * iw);
    }
    unsafeAtomicAdd(&sCnt[bx], 1.f);
    unsafeAtomicAdd(&sCnt[by], 1.f);
    unsafeAtomicAdd(&sCnt[bz], 1.f);
    unsafeAtomicAdd(&sCnt[bw], 1.f);

    // ---- block reduce logpy ----
#pragma unroll
    for (int off = 32; off > 0; off >>= 1) lp += __shfl_down(lp, off);
    if ((tid & 63) == 0) sRed[tid >> 6] = lp;
    __syncthreads();   // covers sRed AND all LDS atomics above

    // ---- flush block partials to one of `copies` global accumulators ----
    float* __restrict__ a = acc + (size_t)(blockIdx.x & copy_mask) * ACC_STRIDE;
    for (int i = tid; i < C * C; i += BLOCK) unsafeAtomicAdd(&a[i], sS[i]);
    if (tid < C) unsafeAtomicAdd(&a[WS_CNT + tid], sCnt[tid]);
    if (tid == 0) {
        float tt = 0.f;
#pragma unroll
        for (int wv = 0; wv < BLOCK / 64; ++wv) tt += sRed[wv];
        unsafeAtomicAdd(&a[WS_LOGP], tt);
    }
}

__global__ void wce_final(const float* __restrict__ acc, float* __restrict__ out,
                          int copies) {
    __shared__ float tot[ACC_USED];
    __shared__ float red[8];
    const int tid = threadIdx.x;

    for (int i = tid; i < ACC_USED; i += 512) {
        float s = 0.f;
        for (int k = 0; k < copies; ++k) s += acc[(size_t)k * ACC_STRIDE + i];
        tot[i] = s;
    }
    __syncthreads();

    float partial = 0.f;
    if (tid < C * C) {
        const int i = tid / C;
        const int j = tid - i * C;
        if (i != j) {
            const float ci = tot[WS_CNT + i], cj = tot[WS_CNT + j];
            if (ci > 0.f && cj > 0.f) {
                const float mcc = tot[i * C + i] / ci - tot[i * C + j] / cj;
                partial = -0.5f * __logf(0.5f * mcc + 0.5f + EPS);
            }
        }
    }
#pragma unroll
    for (int off = 32; off > 0; off >>= 1) partial += __shfl_down(partial, off);
    if ((tid & 63) == 0) red[tid >> 6] = partial;
    __syncthreads();

    if (tid == 0) {
        float lossd = 0.f;
#pragma unroll
        for (int wv = 0; wv < 8; ++wv) lossd += red[wv];
        const float loss = -tot[WS_LOGP] / (float)NPIX;
        out[0] = loss + lossd;
    }
}

extern "C" void kernel_launch(void* const* d_in, const int* in_sizes, int n_in,
                              void* d_out, int out_size, void* d_ws, size_t ws_size,
                              hipStream_t stream) {
    const float* inp = (const float*)d_in[0];
    const float* tgt = (const float*)d_in[1];
    float* acc = (float*)d_ws;
    float* out = (float*)d_out;

    int copies = 1;
    const size_t per = (size_t)ACC_STRIDE * sizeof(float);
    while (copies * 2 <= MAX_COPIES && (size_t)(copies * 2) * per <= ws_size) copies *= 2;

    hipMemsetAsync(acc, 0, (size_t)copies * per, stream);
    wce_main<<<GRID, BLOCK, 0, stream>>>(inp, tgt, acc, copies - 1);
    wce_final<<<1, 512, 0, stream>>>(acc, out, copies);
}